// Round 10
// baseline (233.802 us; speedup 1.0000x reference)
//
#include <hip/hip_runtime.h>
#include <hip/hip_bf16.h>

#define B_ 128
#define S_ 48
#define W_ 12
#define V_ 32000
#define SYM_ 128
#define H_ 256
#define E_ 48
#define R_ 24
#define TM 32

typedef float f32x4 __attribute__((ext_vector_type(4)));

__device__ __forceinline__ float4 fma4(float s, float4 w, float4 a) {
    a.x = fmaf(s, w.x, a.x); a.y = fmaf(s, w.y, a.y);
    a.z = fmaf(s, w.z, a.z); a.w = fmaf(s, w.w, a.w);
    return a;
}

// global -> LDS async copy, 16 B per lane (LDS dest = wave-uniform base + lane*16)
__device__ __forceinline__ void gl_lds16(const float* g, float* l) {
    __builtin_amdgcn_global_load_lds(
        (const __attribute__((address_space(1))) void*)g,
        (__attribute__((address_space(3))) void*)l, 16, 0, 0);
}

// ---- DPP cross-lane sum over 32-lane group (all lanes get the sum) ----
template<int CTRL>
__device__ __forceinline__ float dpp_add_f(float v) {
    int p = __builtin_amdgcn_update_dpp(
        0, __builtin_bit_cast(int, v), CTRL, 0xf, 0xf, true);
    return v + __builtin_bit_cast(float, p);
}
__device__ __forceinline__ float red32(float v) {
    int sw = __builtin_amdgcn_ds_swizzle(__builtin_bit_cast(int, v), 0x401F); // xor16
    v += __builtin_bit_cast(float, sw);
    v = dpp_add_f<0xB1>(v);   // quad_perm [1,0,3,2] : xor1
    v = dpp_add_f<0x4E>(v);   // quad_perm [2,3,0,1] : xor2
    v = dpp_add_f<0x124>(v);  // row_ror:4
    v = dpp_add_f<0x128>(v);  // row_ror:8
    return v;
}

// ---------------------------------------------------------------------------
// Kernel 1: ssum[b,s,c] = sum_w we[story[b,s,w],c]*pe[w,c];  qsum likewise.
// ---------------------------------------------------------------------------
__global__ __launch_bounds__(128) void ssum_kernel(
    const int* __restrict__ story, const int* __restrict__ query,
    const float* __restrict__ we, const float* __restrict__ pe,
    float* __restrict__ ssum, float* __restrict__ qsum)
{
    int i = blockIdx.x;
    int c = threadIdx.x;
    const int* idxp;
    float* outp;
    if (i < B_ * S_) {
        idxp = story + (size_t)i * W_;
        outp = ssum + (size_t)i * SYM_;
    } else {
        int b = i - B_ * S_;
        idxp = query + (size_t)b * W_;
        outp = qsum + (size_t)b * SYM_;
    }
    float acc = 0.f;
#pragma unroll
    for (int w = 0; w < W_; ++w) {
        int id = idxp[w];
        acc = fmaf(we[(size_t)id * SYM_ + c], pe[w * SYM_ + c], acc);
    }
    outp[c] = acc;
}

// ---------------------------------------------------------------------------
// Kernel 2: 2-layer tanh MLP, 128->256->OUT, TM=32 rows per block.
// r10 diagnosis: (a) SMEM s_loads mixed with ds_reads force lgkmcnt(0) per
// kk4 (SMEM retires out-of-order); (b) vmcnt retires in-order, so loads
// issued after staging chain behind HBM latency. Fix: x via per-lane vector
// loads (broadcast addr, L1-hot), issued BEFORE the chunk's staging ops;
// W1 via global_load_lds double-buffer in the FIRST 16KB of the hs pool
// (LDS union: 33.3 KB total -> 4 blocks/CU).
// ---------------------------------------------------------------------------
template<int NQ>
__device__ __forceinline__ void mlp_layer2(
    int t, int row0, const float4* hs4, const float* __restrict__ W2,
    const float* __restrict__ b2, float* __restrict__ out)
{
    const float4* W2_4 = reinterpret_cast<const float4*>(W2);  // [256][NQ]
    for (int idx = t; idx < TM * NQ; idx += 256) {
        int row = idx / NQ, q = idx - row * NQ;
        float4 cw0 = W2_4[0 * NQ + q];
        float4 cw1 = W2_4[1 * NQ + q];
        float4 cw2 = W2_4[2 * NQ + q];
        float4 cw3 = W2_4[3 * NQ + q];
        float4 a = {0, 0, 0, 0};
#pragma unroll 1
        for (int k4 = 0; k4 < H_ / 4 - 1; ++k4) {
            float4 nw0 = W2_4[(size_t)(4 * k4 + 4) * NQ + q];
            float4 nw1 = W2_4[(size_t)(4 * k4 + 5) * NQ + q];
            float4 nw2 = W2_4[(size_t)(4 * k4 + 6) * NQ + q];
            float4 nw3 = W2_4[(size_t)(4 * k4 + 7) * NQ + q];
            float4 h = hs4[row * 65 + k4];
            a = fma4(h.x, cw0, fma4(h.y, cw1, fma4(h.z, cw2, fma4(h.w, cw3, a))));
            cw0 = nw0; cw1 = nw1; cw2 = nw2; cw3 = nw3;
        }
        {
            float4 h = hs4[row * 65 + (H_ / 4 - 1)];
            a = fma4(h.x, cw0, fma4(h.y, cw1, fma4(h.z, cw2, fma4(h.w, cw3, a))));
        }
        float4 bv = reinterpret_cast<const float4*>(b2)[q];
        float4 o;
        o.x = tanhf(a.x + bv.x); o.y = tanhf(a.y + bv.y);
        o.z = tanhf(a.z + bv.z); o.w = tanhf(a.w + bv.w);
        reinterpret_cast<float4*>(out + (size_t)(row0 + row) * (NQ * 4))[q] = o;
    }
}

__global__ __launch_bounds__(256) void mlp_kernel(
    const float* __restrict__ x, int M,
    const float* __restrict__ W1e, const float* __restrict__ b1e,
    const float* __restrict__ W2e, const float* __restrict__ b2e,
    int nE,
    const float* __restrict__ W1r, const float* __restrict__ b1r,
    const float* __restrict__ W2r, const float* __restrict__ b2r,
    float* __restrict__ outE,   // [nE][M][48]
    float* __restrict__ outR)   // [nR][M][24]
{
    int m = blockIdx.y;
    int row0 = blockIdx.x * TM;
    const float *W1, *b1, *W2, *b2;
    float* out;
    int OUT;
    if (m < nE) {
        W1 = W1e + (size_t)m * SYM_ * H_;
        b1 = b1e + (size_t)m * H_;
        W2 = W2e + (size_t)m * H_ * E_;
        b2 = b2e + (size_t)m * E_;
        out = outE + (size_t)m * M * E_;
        OUT = E_;
    } else {
        int mr = m - nE;
        W1 = W1r + (size_t)mr * SYM_ * H_;
        b1 = b1r + (size_t)mr * H_;
        W2 = W2r + (size_t)mr * H_ * R_;
        b2 = b2r + (size_t)mr * R_;
        out = outR + (size_t)mr * M * R_;
        OUT = R_;
    }

    int t = threadIdx.x;
    const int wv = t >> 6;      // wave id (rows 8wv..8wv+7)
    const int cq = t & 63;      // col-quad (cols 4cq..4cq+3)

    // LDS union: 33.3 KB pool. First 16 KB = W1 chunk double-buffer during
    // layer 1; whole pool = padded h tile afterwards (barrier-separated).
    __shared__ __align__(16) float4 pool4[TM * 65];
    float* wlds = reinterpret_cast<float*>(pool4);

    // per-lane x pointer (same addr across the wave -> 1 L1 access/load;
    // v-loads, NOT s_loads: keeps SMEM out of the lgkm domain)
    const float* xw = x + (size_t)(row0 + 8 * wv) * SYM_;

#define STAGE1(c, p) { \
        const float* gsrc = W1 + (c) * 2048 + t * 4; \
        gl_lds16(gsrc,        wlds + (p) * 2048 + wv * 256); \
        gl_lds16(gsrc + 1024, wlds + (p) * 2048 + 1024 + wv * 256); }

    float4 A0 = {0, 0, 0, 0}, A1 = A0, A2 = A0, A3 = A0,
           A4 = A0, A5 = A0, A6 = A0, A7 = A0;

    STAGE1(0, 0)
    asm volatile("s_waitcnt vmcnt(0)" ::: "memory");
    __syncthreads();

#pragma unroll 1
    for (int c = 0; c < 16; ++c) {
        const int p = c & 1;
        // x loads for BOTH kk4 of this chunk, issued BEFORE the staging ops
        // so their vmcnt wait does not drain the prefetch (in-order retire).
#define LDX(v, row, xq) float4 v = *reinterpret_cast<const float4*>(xw + (row) * SYM_ + 4 * (xq));
        LDX(xa0, 0, 2 * c)     LDX(xa1, 1, 2 * c)     LDX(xa2, 2, 2 * c)     LDX(xa3, 3, 2 * c)
        LDX(xa4, 4, 2 * c)     LDX(xa5, 5, 2 * c)     LDX(xa6, 6, 2 * c)     LDX(xa7, 7, 2 * c)
        LDX(xb0, 0, 2 * c + 1) LDX(xb1, 1, 2 * c + 1) LDX(xb2, 2, 2 * c + 1) LDX(xb3, 3, 2 * c + 1)
        LDX(xb4, 4, 2 * c + 1) LDX(xb5, 5, 2 * c + 1) LDX(xb6, 6, 2 * c + 1) LDX(xb7, 7, 2 * c + 1)
#undef LDX
        if (c + 1 < 16) STAGE1(c + 1, p ^ 1)
        const float* wl = wlds + p * 2048;
        {   // kk4 = 0 : W rows 0..3 of chunk
            float4 w0 = *reinterpret_cast<const float4*>(wl + 0 * 256 + 4 * cq);
            float4 w1 = *reinterpret_cast<const float4*>(wl + 1 * 256 + 4 * cq);
            float4 w2 = *reinterpret_cast<const float4*>(wl + 2 * 256 + 4 * cq);
            float4 w3 = *reinterpret_cast<const float4*>(wl + 3 * 256 + 4 * cq);
            A0 = fma4(xa0.x, w0, fma4(xa0.y, w1, fma4(xa0.z, w2, fma4(xa0.w, w3, A0))));
            A1 = fma4(xa1.x, w0, fma4(xa1.y, w1, fma4(xa1.z, w2, fma4(xa1.w, w3, A1))));
            A2 = fma4(xa2.x, w0, fma4(xa2.y, w1, fma4(xa2.z, w2, fma4(xa2.w, w3, A2))));
            A3 = fma4(xa3.x, w0, fma4(xa3.y, w1, fma4(xa3.z, w2, fma4(xa3.w, w3, A3))));
            A4 = fma4(xa4.x, w0, fma4(xa4.y, w1, fma4(xa4.z, w2, fma4(xa4.w, w3, A4))));
            A5 = fma4(xa5.x, w0, fma4(xa5.y, w1, fma4(xa5.z, w2, fma4(xa5.w, w3, A5))));
            A6 = fma4(xa6.x, w0, fma4(xa6.y, w1, fma4(xa6.z, w2, fma4(xa6.w, w3, A6))));
            A7 = fma4(xa7.x, w0, fma4(xa7.y, w1, fma4(xa7.z, w2, fma4(xa7.w, w3, A7))));
        }
        {   // kk4 = 1 : W rows 4..7 of chunk
            float4 w0 = *reinterpret_cast<const float4*>(wl + 4 * 256 + 4 * cq);
            float4 w1 = *reinterpret_cast<const float4*>(wl + 5 * 256 + 4 * cq);
            float4 w2 = *reinterpret_cast<const float4*>(wl + 6 * 256 + 4 * cq);
            float4 w3 = *reinterpret_cast<const float4*>(wl + 7 * 256 + 4 * cq);
            A0 = fma4(xb0.x, w0, fma4(xb0.y, w1, fma4(xb0.z, w2, fma4(xb0.w, w3, A0))));
            A1 = fma4(xb1.x, w0, fma4(xb1.y, w1, fma4(xb1.z, w2, fma4(xb1.w, w3, A1))));
            A2 = fma4(xb2.x, w0, fma4(xb2.y, w1, fma4(xb2.z, w2, fma4(xb2.w, w3, A2))));
            A3 = fma4(xb3.x, w0, fma4(xb3.y, w1, fma4(xb3.z, w2, fma4(xb3.w, w3, A3))));
            A4 = fma4(xb4.x, w0, fma4(xb4.y, w1, fma4(xb4.z, w2, fma4(xb4.w, w3, A4))));
            A5 = fma4(xb5.x, w0, fma4(xb5.y, w1, fma4(xb5.z, w2, fma4(xb5.w, w3, A5))));
            A6 = fma4(xb6.x, w0, fma4(xb6.y, w1, fma4(xb6.z, w2, fma4(xb6.w, w3, A6))));
            A7 = fma4(xb7.x, w0, fma4(xb7.y, w1, fma4(xb7.z, w2, fma4(xb7.w, w3, A7))));
        }
        asm volatile("s_waitcnt vmcnt(0)" ::: "memory");  // next chunk staged
        __syncthreads();                                   // all done reading buf p
    }
#undef STAGE1

    // write h into the pool (overlaps the W dbuf region; loop-end barrier
    // guarantees every wave finished its last ds_read before these writes)
    {
        float4 bb = reinterpret_cast<const float4*>(b1)[cq];
        float4 v;
#define H1ROW(i, acc) \
        v.x = tanhf(acc.x + bb.x); v.y = tanhf(acc.y + bb.y); \
        v.z = tanhf(acc.z + bb.z); v.w = tanhf(acc.w + bb.w); \
        pool4[(8 * wv + i) * 65 + cq] = v;
        H1ROW(0, A0) H1ROW(1, A1) H1ROW(2, A2) H1ROW(3, A3)
        H1ROW(4, A4) H1ROW(5, A5) H1ROW(6, A6) H1ROW(7, A7)
#undef H1ROW
    }
    __syncthreads();

    // ---- layer 2 ----
    if (OUT == E_) mlp_layer2<12>(t, row0, pool4, W2, b2, out);
    else           mlp_layer2<6>(t, row0, pool4, W2, b2, out);
}

// ---------------------------------------------------------------------------
// Kernel 3: sequential TPR scan, barrier-free; r-reduction via 1 ds_swizzle
// + 4 DPP adds. grid (6, B), 256 thr = 8 subwaves of 32; lane<24 owns r.
// ---------------------------------------------------------------------------
__global__ __launch_bounds__(256) void scan_kernel(
    const float* __restrict__ eg,   // [2][B][S][48]
    const float* __restrict__ rg,   // [3][B][S][24]
    float* __restrict__ TPR)        // [B][48][48][24]
{
    const int b = blockIdx.y;
    const int g = threadIdx.x >> 5;
    const int l = threadIdx.x & 31;
    const int f = blockIdx.x * 8 + g;
    const bool act = l < R_;
    const int rc = act ? l : 0;
    const float msk = act ? 1.f : 0.f;

    f32x4 T0 = {0.f, 0.f, 0.f, 0.f};
    f32x4 T1 = T0, T2 = T0, T3 = T0, T4 = T0, T5 = T0,
          T6 = T0, T7 = T0, T8 = T0, T9 = T0, T10 = T0, T11 = T0;

    const size_t bs48 = (size_t)b * S_ * 48;
    const size_t bs24 = (size_t)b * S_ * 24;
    const float* e1g = eg + bs48;
    const float* e2g = eg + (size_t)B_ * S_ * 48 + bs48;
    const float* r1g = rg + bs24;
    const float* r2g = rg + (size_t)B_ * S_ * 24 + bs24;
    const float* r3g = rg + (size_t)2 * B_ * S_ * 24 + bs24;

    for (int s = 0; s < S_; ++s) {
        float r1v = r1g[s * 24 + rc] * msk;
        float r2v = r2g[s * 24 + rc] * msk;
        float r3v = r3g[s * 24 + rc] * msk;
        const f32x4* e1q = reinterpret_cast<const f32x4*>(e1g + s * 48);  // uniform -> s_load
        const f32x4* e2q = reinterpret_cast<const f32x4*>(e2g + s * 48);
        float e1f = (e1g + s * 48)[f];
        float e2f = (e2g + s * 48)[f];

        f32x4 s1v = {0.f, 0.f, 0.f, 0.f};
        f32x4 s2v = s1v;
#define DOTI(i) { f32x4 a = e1q[i]; f32x4 c = e2q[i]; \
        s1v = __builtin_elementwise_fma(a, T##i, s1v); \
        s2v = __builtin_elementwise_fma(c, T##i, s2v); }
        DOTI(0) DOTI(1) DOTI(2) DOTI(3) DOTI(4) DOTI(5)
        DOTI(6) DOTI(7) DOTI(8) DOTI(9) DOTI(10) DOTI(11)
#undef DOTI
        float s1 = (s1v[0] + s1v[1]) + (s1v[2] + s1v[3]);
        float s2 = (s2v[0] + s2v[1]) + (s2v[2] + s2v[3]);

        float p0 = red32(r1v * s1);   // w_hat[f]
        float p1 = red32(r2v * s1);   // m_hat[f]
        float p2 = red32(r3v * s2);   // b_hat[f]

        float wm = fmaf(r1v, e2f - p0, r2v * (p0 - p1));
        float bl = r3v * (e1f - p2);
        f32x4 w4 = {wm, wm, wm, wm};
        f32x4 b4 = {bl, bl, bl, bl};
#define UPDI(i) { f32x4 a = e1q[i]; f32x4 c = e2q[i]; \
        T##i = __builtin_elementwise_fma(a, w4, __builtin_elementwise_fma(c, b4, T##i)); }
        UPDI(0) UPDI(1) UPDI(2) UPDI(3) UPDI(4) UPDI(5)
        UPDI(6) UPDI(7) UPDI(8) UPDI(9) UPDI(10) UPDI(11)
#undef UPDI
    }

    if (act) {
        float* outp = TPR + ((size_t)b * E_ * 48 + f) * 24 + l;
#define STI(i) { f32x4 v = T##i; \
        outp[(size_t)(4 * i + 0) * 48 * 24] = v[0]; \
        outp[(size_t)(4 * i + 1) * 48 * 24] = v[1]; \
        outp[(size_t)(4 * i + 2) * 48 * 24] = v[2]; \
        outp[(size_t)(4 * i + 3) * 48 * 24] = v[3]; }
        STI(0) STI(1) STI(2) STI(3) STI(4) STI(5)
        STI(6) STI(7) STI(8) STI(9) STI(10) STI(11)
#undef STI
    }
}

// ---------------------------------------------------------------------------
// Kernel 4: inference contractions + LayerNorms. One block per batch.
// ---------------------------------------------------------------------------
__global__ __launch_bounds__(576) void infer_kernel(
    const float* __restrict__ TPR,   // [B][48][48][24]
    const float* __restrict__ qe1,   // [B][48]
    const float* __restrict__ qr,    // [3][B][24]
    const float* __restrict__ ln_gain, const float* __restrict__ ln_bias,  // [3][48]
    float* __restrict__ isum)        // [B][48]
{
    int b = blockIdx.x;
    int t = threadIdx.x;
    int f = t / 12;
    int j = t % 12;
    int half = j / 6;
    int q4 = j % 6;

    __shared__ float part[48][13];
    __shared__ float xv[48];
    __shared__ float av[48];
    __shared__ float acc3[48];

    const float* Tb = TPR + (size_t)b * E_ * 48 * 24;
    if (t < 48) {
        av[t] = qe1[b * 48 + t];
        acc3[t] = 0.f;
    }
    __syncthreads();

    for (int c = 0; c < 3; ++c) {
        const float* qrc = qr + ((size_t)c * B_ + b) * 24;
        float4 qq = *reinterpret_cast<const float4*>(qrc + 4 * q4);
        float p = 0.f;
        int e0 = half * 24;
#pragma unroll 8
        for (int k = 0; k < 24; ++k) {
            int e = e0 + k;
            float4 v = *reinterpret_cast<const float4*>(Tb + ((size_t)e * 48 + f) * 24 + 4 * q4);
            float d = fmaf(qq.x, v.x, fmaf(qq.y, v.y, fmaf(qq.z, v.z, qq.w * v.w)));
            p = fmaf(av[e], d, p);
        }
        part[f][j] = p;
        __syncthreads();
        if (t < 48) {
            float x = 0.f;
#pragma unroll
            for (int jj = 0; jj < 12; ++jj) x += part[t][jj];
            xv[t] = x;
        }
        __syncthreads();
        if (t < 48) {
            float mu = 0.f;
#pragma unroll
            for (int jj = 0; jj < 48; ++jj) mu += xv[jj];
            mu *= (1.f / 48.f);
            float var = 0.f;
#pragma unroll
            for (int jj = 0; jj < 48; ++jj) {
                float d = xv[jj] - mu;
                var = fmaf(d, d, var);
            }
            var *= (1.f / 48.f);
            float inv = 1.f / sqrtf(var + 1e-6f);
            float o = ln_gain[c * 48 + t] * (xv[t] - mu) * inv + ln_bias[c * 48 + t];
            av[t] = o;
            acc3[t] += o;
        }
        __syncthreads();
    }
    if (t < 48) isum[b * 48 + t] = acc3[t];
}

// ---------------------------------------------------------------------------
// Kernel 5: logits[b,v] = sum_e isum[b,e] * Z[e,v]
// ---------------------------------------------------------------------------
__global__ __launch_bounds__(256) void logits_kernel(
    const float* __restrict__ isum,  // [B][48]
    const float* __restrict__ Z,     // [48][V]
    float* __restrict__ out)         // [B][V]
{
    int v = blockIdx.x * 256 + threadIdx.x;
    int b0 = blockIdx.y * (B_ / 4);
    float z[E_];
#pragma unroll
    for (int e = 0; e < E_; ++e) z[e] = Z[(size_t)e * V_ + v];
    for (int b = b0; b < b0 + B_ / 4; ++b) {
        float a = 0.f;
#pragma unroll
        for (int e = 0; e < E_; ++e) a = fmaf(isum[b * 48 + e], z[e], a);
        out[(size_t)b * V_ + v] = a;
    }
}

// ---------------------------------------------------------------------------
extern "C" void kernel_launch(void* const* d_in, const int* in_sizes, int n_in,
                              void* d_out, int out_size, void* d_ws, size_t ws_size,
                              hipStream_t stream) {
    const int* story  = (const int*)d_in[0];
    const int* query  = (const int*)d_in[1];
    const float* we   = (const float*)d_in[2];
    const float* pe   = (const float*)d_in[3];
    const float* Z    = (const float*)d_in[4];
    const float* ue_W1 = (const float*)d_in[5];
    const float* ue_b1 = (const float*)d_in[6];
    const float* ue_W2 = (const float*)d_in[7];
    const float* ue_b2 = (const float*)d_in[8];
    const float* ur_W1 = (const float*)d_in[9];
    const float* ur_b1 = (const float*)d_in[10];
    const float* ur_W2 = (const float*)d_in[11];
    const float* ur_b2 = (const float*)d_in[12];
    const float* ie_W1 = (const float*)d_in[13];
    const float* ie_b1 = (const float*)d_in[14];
    const float* ie_W2 = (const float*)d_in[15];
    const float* ie_b2 = (const float*)d_in[16];
    const float* ir_W1 = (const float*)d_in[17];
    const float* ir_b1 = (const float*)d_in[18];
    const float* ir_W2 = (const float*)d_in[19];
    const float* ir_b2 = (const float*)d_in[20];
    const float* ln_g  = (const float*)d_in[21];
    const float* ln_b  = (const float*)d_in[22];
    float* out = (float*)d_out;

    float* ws = (float*)d_ws;
    float* ssum = ws;                                  // 786432
    float* qsum = ssum + (size_t)B_ * S_ * SYM_;       // 16384
    float* eout = qsum + (size_t)B_ * SYM_;            // 589824
    float* rout = eout + (size_t)2 * B_ * S_ * E_;     // 442368
    float* qe1  = rout + (size_t)3 * B_ * S_ * R_;     // 6144
    float* qrr  = qe1 + (size_t)B_ * E_;               // 9216
    float* TPR  = qrr + (size_t)3 * B_ * R_;           // 3538944
    float* isum = TPR + (size_t)B_ * E_ * 48 * 24;     // 6144

    ssum_kernel<<<B_ * S_ + B_, 128, 0, stream>>>(story, query, we, pe, ssum, qsum);

    mlp_kernel<<<dim3((B_ * S_) / TM, 5), 256, 0, stream>>>(
        ssum, B_ * S_, ue_W1, ue_b1, ue_W2, ue_b2, 2,
        ur_W1, ur_b1, ur_W2, ur_b2, eout, rout);

    mlp_kernel<<<dim3(B_ / TM, 4), 256, 0, stream>>>(
        qsum, B_, ie_W1, ie_b1, ie_W2, ie_b2, 1,
        ir_W1, ir_b1, ir_W2, ir_b2, qe1, qrr);

    scan_kernel<<<dim3(6, B_), 256, 0, stream>>>(eout, rout, TPR);

    infer_kernel<<<B_, 576, 0, stream>>>(TPR, qe1, qrr, ln_g, ln_b, isum);

    logits_kernel<<<dim3(V_ / 256, 4), 256, 0, stream>>>(isum, Z, out);
}

// Round 11
// 197.918 us; speedup vs baseline: 1.1813x; 1.1813x over previous
//
#include <hip/hip_runtime.h>
#include <hip/hip_bf16.h>

#define B_ 128
#define S_ 48
#define W_ 12
#define V_ 32000
#define SYM_ 128
#define H_ 256
#define E_ 48
#define R_ 24
#define TM 32

typedef float f32x4 __attribute__((ext_vector_type(4)));

__device__ __forceinline__ float4 fma4(float s, float4 w, float4 a) {
    a.x = fmaf(s, w.x, a.x); a.y = fmaf(s, w.y, a.y);
    a.z = fmaf(s, w.z, a.z); a.w = fmaf(s, w.w, a.w);
    return a;
}

// global -> LDS async copy, 16 B per lane (LDS dest = wave-uniform base + lane*16)
__device__ __forceinline__ void gl_lds16(const float* g, float* l) {
    __builtin_amdgcn_global_load_lds(
        (const __attribute__((address_space(1))) void*)g,
        (__attribute__((address_space(3))) void*)l, 16, 0, 0);
}

// ---- DPP cross-lane sum over 32-lane group (all lanes get the sum) ----
template<int CTRL>
__device__ __forceinline__ float dpp_add_f(float v) {
    int p = __builtin_amdgcn_update_dpp(
        0, __builtin_bit_cast(int, v), CTRL, 0xf, 0xf, true);
    return v + __builtin_bit_cast(float, p);
}
__device__ __forceinline__ float red32(float v) {
    int sw = __builtin_amdgcn_ds_swizzle(__builtin_bit_cast(int, v), 0x401F); // xor16
    v += __builtin_bit_cast(float, sw);
    v = dpp_add_f<0xB1>(v);   // quad_perm xor1
    v = dpp_add_f<0x4E>(v);   // quad_perm xor2
    v = dpp_add_f<0x124>(v);  // row_ror:4
    v = dpp_add_f<0x128>(v);  // row_ror:8
    return v;
}

// ---------------------------------------------------------------------------
// Kernel 1: ssum[b,s,c] = sum_w we[story[b,s,w],c]*pe[w,c];  qsum likewise.
// ---------------------------------------------------------------------------
__global__ __launch_bounds__(128) void ssum_kernel(
    const int* __restrict__ story, const int* __restrict__ query,
    const float* __restrict__ we, const float* __restrict__ pe,
    float* __restrict__ ssum, float* __restrict__ qsum)
{
    int i = blockIdx.x;
    int c = threadIdx.x;
    const int* idxp;
    float* outp;
    if (i < B_ * S_) {
        idxp = story + (size_t)i * W_;
        outp = ssum + (size_t)i * SYM_;
    } else {
        int b = i - B_ * S_;
        idxp = query + (size_t)b * W_;
        outp = qsum + (size_t)b * SYM_;
    }
    float acc = 0.f;
#pragma unroll
    for (int w = 0; w < W_; ++w) {
        int id = idxp[w];
        acc = fmaf(we[(size_t)id * SYM_ + c], pe[w * SYM_ + c], acc);
    }
    outp[c] = acc;
}

// ---------------------------------------------------------------------------
// Kernel 2: 2-layer tanh MLP, 128->256->OUT, TM=32 rows per block.
// T3/T4 structure (r11): W1 streamed through a 3-slot LDS ring staged 2
// chunks ahead via global_load_lds; per-iter COUNTED asm vmcnt(2) + RAW
// s_barrier (no __syncthreads -> no vmcnt(0) drain). Wave owns 8 rows x
// all 256 cols: x via wave-uniform s_loads (SMEM pipe, not vmcnt/VALU),
// W via ONE contiguous 1KB ds_read_b128 per k (lane = col-quad,
// conflict-free). Per chunk/wave: 8 ds + 256 FMA -> VALU-bound.
// ---------------------------------------------------------------------------
template<int NQ>
__device__ __forceinline__ void mlp_layer2(
    int t, int row0, const float4* hs4, const float* __restrict__ W2,
    const float* __restrict__ b2, float* __restrict__ out)
{
    const float4* W2_4 = reinterpret_cast<const float4*>(W2);  // [256][NQ]
    for (int idx = t; idx < TM * NQ; idx += 256) {
        int row = idx / NQ, q = idx - row * NQ;
        float4 cw0 = W2_4[0 * NQ + q];
        float4 cw1 = W2_4[1 * NQ + q];
        float4 cw2 = W2_4[2 * NQ + q];
        float4 cw3 = W2_4[3 * NQ + q];
        float4 a = {0, 0, 0, 0};
#pragma unroll 1
        for (int k4 = 0; k4 < H_ / 4 - 1; ++k4) {
            float4 nw0 = W2_4[(size_t)(4 * k4 + 4) * NQ + q];
            float4 nw1 = W2_4[(size_t)(4 * k4 + 5) * NQ + q];
            float4 nw2 = W2_4[(size_t)(4 * k4 + 6) * NQ + q];
            float4 nw3 = W2_4[(size_t)(4 * k4 + 7) * NQ + q];
            float4 h = hs4[row * 65 + k4];
            a = fma4(h.x, cw0, fma4(h.y, cw1, fma4(h.z, cw2, fma4(h.w, cw3, a))));
            cw0 = nw0; cw1 = nw1; cw2 = nw2; cw3 = nw3;
        }
        {
            float4 h = hs4[row * 65 + (H_ / 4 - 1)];
            a = fma4(h.x, cw0, fma4(h.y, cw1, fma4(h.z, cw2, fma4(h.w, cw3, a))));
        }
        float4 bv = reinterpret_cast<const float4*>(b2)[q];
        float4 o;
        o.x = tanhf(a.x + bv.x); o.y = tanhf(a.y + bv.y);
        o.z = tanhf(a.z + bv.z); o.w = tanhf(a.w + bv.w);
        reinterpret_cast<float4*>(out + (size_t)(row0 + row) * (NQ * 4))[q] = o;
    }
}

__global__ __launch_bounds__(256) void mlp_kernel(
    const float* __restrict__ x, int M,
    const float* __restrict__ W1e, const float* __restrict__ b1e,
    const float* __restrict__ W2e, const float* __restrict__ b2e,
    int nE,
    const float* __restrict__ W1r, const float* __restrict__ b1r,
    const float* __restrict__ W2r, const float* __restrict__ b2r,
    float* __restrict__ outE,   // [nE][M][48]
    float* __restrict__ outR)   // [nR][M][24]
{
    int m = blockIdx.y;
    int row0 = blockIdx.x * TM;
    const float *W1, *b1, *W2, *b2;
    float* out;
    int OUT;
    if (m < nE) {
        W1 = W1e + (size_t)m * SYM_ * H_;
        b1 = b1e + (size_t)m * H_;
        W2 = W2e + (size_t)m * H_ * E_;
        b2 = b2e + (size_t)m * E_;
        out = outE + (size_t)m * M * E_;
        OUT = E_;
    } else {
        int mr = m - nE;
        W1 = W1r + (size_t)mr * SYM_ * H_;
        b1 = b1r + (size_t)mr * H_;
        W2 = W2r + (size_t)mr * H_ * R_;
        b2 = b2r + (size_t)mr * R_;
        out = outR + (size_t)mr * M * R_;
        OUT = R_;
    }

    int t = threadIdx.x;
    const int wv = t >> 6;      // wave owns rows 8wv..8wv+7 (all 256 cols)
    const int l = t & 63;       // lane = col-quad (cols 4l..4l+3)

    // LDS union: 33.3 KB pool; first 24 KB = 3-slot W1 ring during layer 1,
    // whole pool = padded h tile afterwards (barrier-separated).
    __shared__ __align__(16) float4 pool4[TM * 65];
    float* wlds = reinterpret_cast<float*>(pool4);

    // wave-uniform x row base -> SGPR -> x reads are s_loads (SMEM pipe)
    const int xoff = __builtin_amdgcn_readfirstlane((row0 + 8 * wv) * SYM_);
    const float* xw = x + xoff;

    // stage chunk c (8 k-rows, 8KB) into ring slot c%3; each wave stages its
    // own 2KB (2 ops x 64 lanes x 16B), linear dest = base + lane*16.
#define STAGE(c) { \
    const float* gsrc = W1 + (c) * 2048 + t * 4; \
    float* dst = wlds + ((c) % 3) * 2048 + wv * 256; \
    gl_lds16(gsrc, dst); \
    gl_lds16(gsrc + 1024, dst + 1024); }

#define CHUNK_COMPUTE(c_) { \
    const float* wl = wlds + ((c_) % 3) * 2048; \
    const float* xc = xw + (c_) * 8; \
    _Pragma("unroll") \
    for (int k = 0; k < 8; ++k) { \
        float4 w4 = *reinterpret_cast<const float4*>(wl + k * 256 + l * 4); \
        A0 = fma4(xc[0 * SYM_ + k], w4, A0); \
        A1 = fma4(xc[1 * SYM_ + k], w4, A1); \
        A2 = fma4(xc[2 * SYM_ + k], w4, A2); \
        A3 = fma4(xc[3 * SYM_ + k], w4, A3); \
        A4 = fma4(xc[4 * SYM_ + k], w4, A4); \
        A5 = fma4(xc[5 * SYM_ + k], w4, A5); \
        A6 = fma4(xc[6 * SYM_ + k], w4, A6); \
        A7 = fma4(xc[7 * SYM_ + k], w4, A7); \
    } }

    float4 A0 = {0, 0, 0, 0}, A1 = A0, A2 = A0, A3 = A0,
           A4 = A0, A5 = A0, A6 = A0, A7 = A0;

    STAGE(0)
    STAGE(1)

#pragma unroll 1
    for (int c = 0; c < 15; ++c) {
        // counted wait: chunk c's 2 ops done, chunk c+1's 2 still in flight
        asm volatile("s_waitcnt vmcnt(2)" ::: "memory");
        __builtin_amdgcn_s_barrier();
        if (c + 2 < 16) STAGE(c + 2)   // slot (c+2)%3: free (read in iter c-1)
        CHUNK_COMPUTE(c)
    }
    // epilogue: chunk 15 (nothing left in flight after this wait)
    asm volatile("s_waitcnt vmcnt(0)" ::: "memory");
    __builtin_amdgcn_s_barrier();
    CHUNK_COMPUTE(15)
#undef CHUNK_COMPUTE
#undef STAGE

    __syncthreads();   // all waves done reading ring before h overwrites pool

    {
        float4 bb = reinterpret_cast<const float4*>(b1)[l];
        float4 v;
#define H1ROW(i, acc) \
        v.x = tanhf(acc.x + bb.x); v.y = tanhf(acc.y + bb.y); \
        v.z = tanhf(acc.z + bb.z); v.w = tanhf(acc.w + bb.w); \
        pool4[(8 * wv + i) * 65 + l] = v;
        H1ROW(0, A0) H1ROW(1, A1) H1ROW(2, A2) H1ROW(3, A3)
        H1ROW(4, A4) H1ROW(5, A5) H1ROW(6, A6) H1ROW(7, A7)
#undef H1ROW
    }
    __syncthreads();

    // ---- layer 2 ----
    if (OUT == E_) mlp_layer2<12>(t, row0, pool4, W2, b2, out);
    else           mlp_layer2<6>(t, row0, pool4, W2, b2, out);
}

// ---------------------------------------------------------------------------
// Kernel 3: sequential TPR scan, barrier-free; r-reduction via 1 ds_swizzle
// + 4 DPP adds. grid (6, B), 256 thr = 8 subwaves of 32; lane<24 owns r.
// ---------------------------------------------------------------------------
__global__ __launch_bounds__(256) void scan_kernel(
    const float* __restrict__ eg,   // [2][B][S][48]
    const float* __restrict__ rg,   // [3][B][S][24]
    float* __restrict__ TPR)        // [B][48][48][24]
{
    const int b = blockIdx.y;
    const int g = threadIdx.x >> 5;
    const int l = threadIdx.x & 31;
    const int f = blockIdx.x * 8 + g;
    const bool act = l < R_;
    const int rc = act ? l : 0;
    const float msk = act ? 1.f : 0.f;

    f32x4 T0 = {0.f, 0.f, 0.f, 0.f};
    f32x4 T1 = T0, T2 = T0, T3 = T0, T4 = T0, T5 = T0,
          T6 = T0, T7 = T0, T8 = T0, T9 = T0, T10 = T0, T11 = T0;

    const size_t bs48 = (size_t)b * S_ * 48;
    const size_t bs24 = (size_t)b * S_ * 24;
    const float* e1g = eg + bs48;
    const float* e2g = eg + (size_t)B_ * S_ * 48 + bs48;
    const float* r1g = rg + bs24;
    const float* r2g = rg + (size_t)B_ * S_ * 24 + bs24;
    const float* r3g = rg + (size_t)2 * B_ * S_ * 24 + bs24;

    for (int s = 0; s < S_; ++s) {
        float r1v = r1g[s * 24 + rc] * msk;
        float r2v = r2g[s * 24 + rc] * msk;
        float r3v = r3g[s * 24 + rc] * msk;
        const f32x4* e1q = reinterpret_cast<const f32x4*>(e1g + s * 48);  // uniform -> s_load
        const f32x4* e2q = reinterpret_cast<const f32x4*>(e2g + s * 48);
        float e1f = (e1g + s * 48)[f];
        float e2f = (e2g + s * 48)[f];

        f32x4 s1v = {0.f, 0.f, 0.f, 0.f};
        f32x4 s2v = s1v;
#define DOTI(i) { f32x4 a = e1q[i]; f32x4 c = e2q[i]; \
        s1v = __builtin_elementwise_fma(a, T##i, s1v); \
        s2v = __builtin_elementwise_fma(c, T##i, s2v); }
        DOTI(0) DOTI(1) DOTI(2) DOTI(3) DOTI(4) DOTI(5)
        DOTI(6) DOTI(7) DOTI(8) DOTI(9) DOTI(10) DOTI(11)
#undef DOTI
        float s1 = (s1v[0] + s1v[1]) + (s1v[2] + s1v[3]);
        float s2 = (s2v[0] + s2v[1]) + (s2v[2] + s2v[3]);

        float p0 = red32(r1v * s1);   // w_hat[f]
        float p1 = red32(r2v * s1);   // m_hat[f]
        float p2 = red32(r3v * s2);   // b_hat[f]

        float wm = fmaf(r1v, e2f - p0, r2v * (p0 - p1));
        float bl = r3v * (e1f - p2);
        f32x4 w4 = {wm, wm, wm, wm};
        f32x4 b4 = {bl, bl, bl, bl};
#define UPDI(i) { f32x4 a = e1q[i]; f32x4 c = e2q[i]; \
        T##i = __builtin_elementwise_fma(a, w4, __builtin_elementwise_fma(c, b4, T##i)); }
        UPDI(0) UPDI(1) UPDI(2) UPDI(3) UPDI(4) UPDI(5)
        UPDI(6) UPDI(7) UPDI(8) UPDI(9) UPDI(10) UPDI(11)
#undef UPDI
    }

    if (act) {
        float* outp = TPR + ((size_t)b * E_ * 48 + f) * 24 + l;
#define STI(i) { f32x4 v = T##i; \
        outp[(size_t)(4 * i + 0) * 48 * 24] = v[0]; \
        outp[(size_t)(4 * i + 1) * 48 * 24] = v[1]; \
        outp[(size_t)(4 * i + 2) * 48 * 24] = v[2]; \
        outp[(size_t)(4 * i + 3) * 48 * 24] = v[3]; }
        STI(0) STI(1) STI(2) STI(3) STI(4) STI(5)
        STI(6) STI(7) STI(8) STI(9) STI(10) STI(11)
#undef STI
    }
}

// ---------------------------------------------------------------------------
// Kernel 4: inference contractions + LayerNorms. One block per batch.
// ---------------------------------------------------------------------------
__global__ __launch_bounds__(576) void infer_kernel(
    const float* __restrict__ TPR,   // [B][48][48][24]
    const float* __restrict__ qe1,   // [B][48]
    const float* __restrict__ qr,    // [3][B][24]
    const float* __restrict__ ln_gain, const float* __restrict__ ln_bias,  // [3][48]
    float* __restrict__ isum)        // [B][48]
{
    int b = blockIdx.x;
    int t = threadIdx.x;
    int f = t / 12;
    int j = t % 12;
    int half = j / 6;
    int q4 = j % 6;

    __shared__ float part[48][13];
    __shared__ float xv[48];
    __shared__ float av[48];
    __shared__ float acc3[48];

    const float* Tb = TPR + (size_t)b * E_ * 48 * 24;
    if (t < 48) {
        av[t] = qe1[b * 48 + t];
        acc3[t] = 0.f;
    }
    __syncthreads();

    for (int c = 0; c < 3; ++c) {
        const float* qrc = qr + ((size_t)c * B_ + b) * 24;
        float4 qq = *reinterpret_cast<const float4*>(qrc + 4 * q4);
        float p = 0.f;
        int e0 = half * 24;
#pragma unroll 8
        for (int k = 0; k < 24; ++k) {
            int e = e0 + k;
            float4 v = *reinterpret_cast<const float4*>(Tb + ((size_t)e * 48 + f) * 24 + 4 * q4);
            float d = fmaf(qq.x, v.x, fmaf(qq.y, v.y, fmaf(qq.z, v.z, qq.w * v.w)));
            p = fmaf(av[e], d, p);
        }
        part[f][j] = p;
        __syncthreads();
        if (t < 48) {
            float x = 0.f;
#pragma unroll
            for (int jj = 0; jj < 12; ++jj) x += part[t][jj];
            xv[t] = x;
        }
        __syncthreads();
        if (t < 48) {
            float mu = 0.f;
#pragma unroll
            for (int jj = 0; jj < 48; ++jj) mu += xv[jj];
            mu *= (1.f / 48.f);
            float var = 0.f;
#pragma unroll
            for (int jj = 0; jj < 48; ++jj) {
                float d = xv[jj] - mu;
                var = fmaf(d, d, var);
            }
            var *= (1.f / 48.f);
            float inv = 1.f / sqrtf(var + 1e-6f);
            float o = ln_gain[c * 48 + t] * (xv[t] - mu) * inv + ln_bias[c * 48 + t];
            av[t] = o;
            acc3[t] += o;
        }
        __syncthreads();
    }
    if (t < 48) isum[b * 48 + t] = acc3[t];
}

// ---------------------------------------------------------------------------
// Kernel 5: logits[b,v] = sum_e isum[b,e] * Z[e,v]
// ---------------------------------------------------------------------------
__global__ __launch_bounds__(256) void logits_kernel(
    const float* __restrict__ isum,  // [B][48]
    const float* __restrict__ Z,     // [48][V]
    float* __restrict__ out)         // [B][V]
{
    int v = blockIdx.x * 256 + threadIdx.x;
    int b0 = blockIdx.y * (B_ / 4);
    float z[E_];
#pragma unroll
    for (int e = 0; e < E_; ++e) z[e] = Z[(size_t)e * V_ + v];
    for (int b = b0; b < b0 + B_ / 4; ++b) {
        float a = 0.f;
#pragma unroll
        for (int e = 0; e < E_; ++e) a = fmaf(isum[b * 48 + e], z[e], a);
        out[(size_t)b * V_ + v] = a;
    }
}

// ---------------------------------------------------------------------------
extern "C" void kernel_launch(void* const* d_in, const int* in_sizes, int n_in,
                              void* d_out, int out_size, void* d_ws, size_t ws_size,
                              hipStream_t stream) {
    const int* story  = (const int*)d_in[0];
    const int* query  = (const int*)d_in[1];
    const float* we   = (const float*)d_in[2];
    const float* pe   = (const float*)d_in[3];
    const float* Z    = (const float*)d_in[4];
    const float* ue_W1 = (const float*)d_in[5];
    const float* ue_b1 = (const float*)d_in[6];
    const float* ue_W2 = (const float*)d_in[7];
    const float* ue_b2 = (const float*)d_in[8];
    const float* ur_W1 = (const float*)d_in[9];
    const float* ur_b1 = (const float*)d_in[10];
    const float* ur_W2 = (const float*)d_in[11];
    const float* ur_b2 = (const float*)d_in[12];
    const float* ie_W1 = (const float*)d_in[13];
    const float* ie_b1 = (const float*)d_in[14];
    const float* ie_W2 = (const float*)d_in[15];
    const float* ie_b2 = (const float*)d_in[16];
    const float* ir_W1 = (const float*)d_in[17];
    const float* ir_b1 = (const float*)d_in[18];
    const float* ir_W2 = (const float*)d_in[19];
    const float* ir_b2 = (const float*)d_in[20];
    const float* ln_g  = (const float*)d_in[21];
    const float* ln_b  = (const float*)d_in[22];
    float* out = (float*)d_out;

    float* ws = (float*)d_ws;
    float* ssum = ws;                                  // 786432
    float* qsum = ssum + (size_t)B_ * S_ * SYM_;       // 16384
    float* eout = qsum + (size_t)B_ * SYM_;            // 589824
    float* rout = eout + (size_t)2 * B_ * S_ * E_;     // 442368
    float* qe1  = rout + (size_t)3 * B_ * S_ * R_;     // 6144
    float* qrr  = qe1 + (size_t)B_ * E_;               // 9216
    float* TPR  = qrr + (size_t)3 * B_ * R_;           // 3538944
    float* isum = TPR + (size_t)B_ * E_ * 48 * 24;     // 6144

    ssum_kernel<<<B_ * S_ + B_, 128, 0, stream>>>(story, query, we, pe, ssum, qsum);

    mlp_kernel<<<dim3((B_ * S_) / TM, 5), 256, 0, stream>>>(
        ssum, B_ * S_, ue_W1, ue_b1, ue_W2, ue_b2, 2,
        ur_W1, ur_b1, ur_W2, ur_b2, eout, rout);

    mlp_kernel<<<dim3(B_ / TM, 4), 256, 0, stream>>>(
        qsum, B_, ie_W1, ie_b1, ie_W2, ie_b2, 1,
        ir_W1, ir_b1, ir_W2, ir_b2, qe1, qrr);

    scan_kernel<<<dim3(6, B_), 256, 0, stream>>>(eout, rout, TPR);

    infer_kernel<<<B_, 576, 0, stream>>>(TPR, qe1, qrr, ln_g, ln_b, isum);

    logits_kernel<<<dim3(V_ / 256, 4), 256, 0, stream>>>(isum, Z, out);
}